// Round 4
// baseline (345.989 us; speedup 1.0000x reference)
//
#include <hip/hip_runtime.h>

// GCN forward. All inter-kernel feature traffic in bf16.
//   xb  = bf16(x * dinv_row)                       (fused into scatter)
//   axb = bf16(dd*(Σ_{s} xb[s] + xb[d]))           (agg1, bf16 out)
//   a1  = relu(axb@W1 + b1)                        (MFMA GEMM, bf16 out)
//   h2b = bf16((a1@W2) * dinv_row)                 (MFMA GEMM, bf16 out)
//   agg2+pool: pool[g] += relu(dd*(Σ h2b[s] + h2b[d]) + b2)   (fused, no a2b)
//   out = pool/cnt @ Wfc + bfc
// R19: XCD-sliced aggregation. The gather table (12.8 MB) overflows one XCD's
// 4 MB L2 -> ~37% hit (reuse 1.6x/XCD). Split feature dim into 4 line-aligned
// 32-dim (64 B) slices; slice s is processed only by blocks with bid%8 in
// {2s,2s+1} (default round-robin blockIdx->XCD). Per-XCD working set = 3.2 MB
// (L2-fits), reuse 6.4x -> ~84% L2 hit. Bytes & per-edge instr ~unchanged
// (4 lanes x 16B per edge-slice, 16 edges/wave-load). Correctness does NOT
// depend on the XCD mapping -- only locality does.
// R17: pool fused into agg2 (no a2b); scan2 folded into scan3. 10 dispatches.

constexpr int IN_DIM  = 128;
constexpr int HID     = 256;
constexpr int HID2    = 128;
constexpr int OUT_DIM = 4;
constexpr int NGRAPH  = 64;
constexpr int TP      = 132;  // epilogue LDS tile pitch (shorts)

typedef __attribute__((ext_vector_type(8))) short bf16x8;
typedef __attribute__((ext_vector_type(4))) float f32x4;

__device__ __forceinline__ short f2bf(float f) {
    union { float f; unsigned u; } v; v.f = f;
    unsigned r = v.u + 0x7fff + ((v.u >> 16) & 1);   // RNE
    return (short)(r >> 16);
}
__device__ __forceinline__ float bf2f(short s) {
    union { unsigned u; float f; } v; v.u = ((unsigned)(unsigned short)s) << 16;
    return v.f;
}

// ---------------- W prep (both layers) + count zero + pool zero ----------------

__global__ void wprep_all_kernel(const float* __restrict__ W1, short* __restrict__ W1th,
                                 short* __restrict__ W1tl,
                                 const float* __restrict__ W2, short* __restrict__ W2th,
                                 short* __restrict__ W2tl,
                                 int* __restrict__ count, float* __restrict__ pool, int N) {
    int i = blockIdx.x * blockDim.x + threadIdx.x;
    if (i < IN_DIM * HID) {
        int k = i / HID, n = i % HID;
        float w = W1[i];
        short h = f2bf(w);
        W1th[n * IN_DIM + k] = h;
        W1tl[n * IN_DIM + k] = f2bf(w - bf2f(h));
    }
    if (i < HID * HID2) {
        int k = i / HID2, n = i % HID2;
        float w = W2[i];
        short h = f2bf(w);
        W2th[n * HID + k] = h;
        W2tl[n * HID + k] = f2bf(w - bf2f(h));
    }
    if (i < N) count[i] = 0;
    if (i < NGRAPH * HID2) pool[i] = 0.f;
}

// ---------------- CSR build ----------------
// hist: count in-degree AND record each edge's rank within its dst row.

__global__ void hist_kernel(const int* __restrict__ dst, int* __restrict__ count,
                            ushort* __restrict__ rank, int E) {
    int i = blockIdx.x * blockDim.x + threadIdx.x;
    if (i < E) rank[i] = (ushort)atomicAdd(&count[dst[i]], 1);
}

__global__ void scan1_kernel(const int* __restrict__ count, int* __restrict__ bsums, int N) {
    __shared__ int s[256];
    int t = threadIdx.x, i = blockIdx.x * 256 + t;
    int v = (i < N) ? count[i] : 0;
    s[t] = v; __syncthreads();
    for (int o = 1; o < 256; o <<= 1) {
        int x = (t >= o) ? s[t - o] : 0;
        __syncthreads(); s[t] += x; __syncthreads();
    }
    if (t == 255) bsums[blockIdx.x] = s[255];
}

// scan3: inline-scan the (<=256) raw block sums, then per-element scan of count.
__global__ void scan3_kernel(const int* __restrict__ count, const int* __restrict__ bsums,
                             int* __restrict__ rowptr, float* __restrict__ dinv,
                             int N, int E, int nb) {
    __shared__ int sb[256];
    __shared__ int s[256];
    int t = threadIdx.x, i = blockIdx.x * 256 + t;
    // inclusive scan of raw bsums
    int bv = (t < nb) ? bsums[t] : 0;
    sb[t] = bv; __syncthreads();
    for (int o = 1; o < 256; o <<= 1) {
        int x = (t >= o) ? sb[t - o] : 0;
        __syncthreads(); sb[t] += x; __syncthreads();
    }
    // exclusive prefix for this block (LDS broadcast read)
    int myex = (blockIdx.x == 0) ? 0 : sb[blockIdx.x - 1];
    // per-element scan of count
    int v = (i < N) ? count[i] : 0;
    s[t] = v; __syncthreads();
    for (int o = 1; o < 256; o <<= 1) {
        int x = (t >= o) ? s[t - o] : 0;
        __syncthreads(); s[t] += x; __syncthreads();
    }
    if (i < N) {
        rowptr[i] = myex + s[t] - v;
        dinv[i] = rsqrtf((float)v + 1.0f);
        if (i == 0) rowptr[N] = E;
    }
}

// scatter (no atomics: p = rowptr[dst]+rank) + xb = bf16(x * dinv_row)
__global__ void scatter_scale_kernel(const int* __restrict__ src, const int* __restrict__ dst,
                                     const ushort* __restrict__ rank,
                                     const int* __restrict__ rowptr, ushort* __restrict__ csr,
                                     const float* __restrict__ x, const float* __restrict__ dinv,
                                     ushort* __restrict__ xb, int E, int total2) {
    int i = blockIdx.x * blockDim.x + threadIdx.x;
    if (i < E) {
        int p = rowptr[dst[i]] + (int)rank[i];
        csr[p] = (ushort)src[i];
    }
    if (i < total2) {
        float d = dinv[i >> 6];
        float2 v = ((const float2*)x)[i];
        ushort2 o;
        o.x = (ushort)f2bf(v.x * d);
        o.y = (ushort)f2bf(v.y * d);
        ((ushort2*)xb)[i] = o;
    }
}

// ---------------- split-bf16 LDS-tiled MFMA GEMM, bf16 output ----------------
// Cb[M,N] = post( (Ah[+Al]) @ (Bh+Bl)^T ), B given N x K (transposed).
// Block: 128x128 tile, 256 thr. ALO: A has a lo plane (3 MFMAs) else 2 MFMAs.
// LDS slab = 16x32 tile in MFMA fragment order; single ds_read_b128 per frag.
// C/D layout (16x16x32): col=lane&15, row=(lane>>4)*4+reg [verified m89/m91].
// Epilogue: acc -> padded LDS bf16 tile (pitch TP=132) -> coalesced 16B stores.
// RELU: v=relu(v+bias[col]).  SCALED: v*=dinv[row] (pre-scale for gather table).

template <int K, int N, bool ALO, bool RELU, bool SCALED>
__launch_bounds__(256)
__global__ void gemm_tile_kernel(const short* __restrict__ Ah, const short* __restrict__ Al,
                                 const short* __restrict__ Bh, const short* __restrict__ Bl,
                                 const float* __restrict__ bias,
                                 const float* __restrict__ dinv,
                                 short* __restrict__ Cb, int M) {
    __shared__ __align__(16) short LDSBUF[128 * TP];     // 33792 B >= 32 KB staging
    short (*S)[8][512] = (short (*)[8][512])LDSBUF;      // staging view [4][8][512]

    const int tid  = threadIdx.x;
    const int wave = tid >> 6;
    const int lane = tid & 63;
    const int row0 = blockIdx.y * 128;
    const int col0 = blockIdx.x * 128;

    const int l15 = lane & 15;
    const int kq  = (lane >> 4) * 8;

    f32x4 acc[4][4];
#pragma unroll
    for (int i = 0; i < 4; ++i)
#pragma unroll
        for (int j = 0; j < 4; ++j) acc[i][j] = f32x4{0.f, 0.f, 0.f, 0.f};

    const int mt0 = (wave & 1) * 4;
    const int nt0 = (wave >> 1) * 4;

    for (int kb = 0; kb < K; kb += 32) {
        // ---- staging: constant-bound loops only ----
        if (ALO) {
            const short* gsrc = (wave == 0) ? Ah : (wave == 1) ? Al : (wave == 2) ? Bh : Bl;
            const bool isA = wave < 2;
            const int rb = (isA ? row0 : col0) + l15;
            bf16x8 stg[8];
#pragma unroll
            for (int j = 0; j < 8; ++j) {
                int rr = rb + j * 16;
                if (isA && rr >= M) rr = M - 1;       // clamp tail rows (stores guarded)
                stg[j] = *(const bf16x8*)(gsrc + (size_t)rr * K + kb + kq);
            }
#pragma unroll
            for (int j = 0; j < 8; ++j)
                *(bf16x8*)&S[wave][j][lane * 8] = stg[j];
        } else {
            if (wave < 2) {
                const int rb = row0 + l15;
                bf16x8 stg[4];
#pragma unroll
                for (int j = 0; j < 4; ++j) {
                    int rr = rb + (wave * 4 + j) * 16;
                    if (rr >= M) rr = M - 1;
                    stg[j] = *(const bf16x8*)(Ah + (size_t)rr * K + kb + kq);
                }
#pragma unroll
                for (int j = 0; j < 4; ++j)
                    *(bf16x8*)&S[0][wave * 4 + j][lane * 8] = stg[j];
            } else {
                const short* gsrc = (wave == 2) ? Bh : Bl;
                const int rb = col0 + l15;
                bf16x8 stg[8];
#pragma unroll
                for (int j = 0; j < 8; ++j)
                    stg[j] = *(const bf16x8*)(gsrc + (size_t)(rb + j * 16) * K + kb + kq);
#pragma unroll
                for (int j = 0; j < 8; ++j)
                    *(bf16x8*)&S[wave][j][lane * 8] = stg[j];
            }
        }
        __syncthreads();

        bf16x8 ah[4], al[4], bh[4], bl[4];
#pragma unroll
        for (int i = 0; i < 4; ++i) {
            ah[i] = *(const bf16x8*)&S[0][mt0 + i][lane * 8];
            if (ALO) al[i] = *(const bf16x8*)&S[1][mt0 + i][lane * 8];
            bh[i] = *(const bf16x8*)&S[2][nt0 + i][lane * 8];
            bl[i] = *(const bf16x8*)&S[3][nt0 + i][lane * 8];
        }
#pragma unroll
        for (int i = 0; i < 4; ++i)
#pragma unroll
            for (int j = 0; j < 4; ++j) {
                acc[i][j] = __builtin_amdgcn_mfma_f32_16x16x32_bf16(ah[i], bh[j], acc[i][j], 0, 0, 0);
                acc[i][j] = __builtin_amdgcn_mfma_f32_16x16x32_bf16(ah[i], bl[j], acc[i][j], 0, 0, 0);
                if (ALO)
                    acc[i][j] = __builtin_amdgcn_mfma_f32_16x16x32_bf16(al[i], bh[j], acc[i][j], 0, 0, 0);
            }
        __syncthreads();
    }

    // ---- epilogue: acc -> padded LDS bf16 tile -> coalesced stores ----
    short* T = LDSBUF;                      // 128 x TP shorts
    const int lrow_b = (wave & 1) * 64 + (lane >> 4) * 4;
    const int lcol_b = (wave >> 1) * 64 + l15;
#pragma unroll
    for (int j = 0; j < 4; ++j) {
        int lcol = lcol_b + j * 16;
        float bv = RELU ? bias[col0 + lcol] : 0.f;
#pragma unroll
        for (int i = 0; i < 4; ++i) {
#pragma unroll
            for (int r = 0; r < 4; ++r) {
                int lrow = lrow_b + i * 16 + r;
                float v = acc[i][j][r];
                if (RELU) v = fmaxf(v + bv, 0.f);
                if (SCALED) {
                    int dr = row0 + lrow; if (dr >= M) dr = M - 1;
                    v *= dinv[dr];
                }
                T[lrow * TP + lcol] = f2bf(v);
            }
        }
    }
    __syncthreads();
#pragma unroll
    for (int it = 0; it < 8; ++it) {
        int chunk = it * 256 + tid;          // 2048 chunks of 8 shorts
        int lr = chunk >> 4;
        int lc = (chunk & 15) * 8;
        int grow = row0 + lr;
        if (grow < M)
            *(bf16x8*)(Cb + (size_t)grow * N + col0 + lc) = *(const bf16x8*)&T[lr * TP + lc];
    }
}

// ---------------- XCD-sliced bf16 gather aggregation ----------------
// Grid = ceil(N/8)*8 blocks of 256 thr (4 waves). Block bid:
//   slice = (bid&7)>>1  (feature dims [32*slice, 32*slice+32), one 64B line)
//   seq   = (bid>>3)*2 + (bid&1);  wave w handles node = seq*4 + w.
// With default round-robin blockIdx->XCD, slice s runs only on XCDs {2s,2s+1},
// whose L2 then holds just the 3.2 MB slice of the table (6.4x reuse).
// Per edge: 4 lanes x 16B (sub = lane&3); 16 edge slots (eg = lane>>2) per
// wave-load. Reduce across slots via shfl_xor(4,8,16,32); lanes eg==0 write.
// POOL: bias+relu then block LDS reduce over the 4 nodes -> per-graph-run
// atomicAdd into pool slice (a2b never materialized). !POOL: write oh slice.

template <bool POOL>
__launch_bounds__(256)
__global__ void agg_slice_kernel(const ushort* __restrict__ hb, const float* __restrict__ dinv,
                                 const int* __restrict__ rowptr, const ushort* __restrict__ csr,
                                 const float* __restrict__ bias,
                                 short* __restrict__ oh,
                                 const int* __restrict__ batch, float* __restrict__ pool,
                                 int N) {
    __shared__ float pacc[4][32];
    __shared__ int   sgid[4];

    const int tid  = threadIdx.x;
    const int wave = tid >> 6;
    const int lane = tid & 63;
    const int bid  = blockIdx.x;
    const int slice = (bid & 7) >> 1;
    const int seq   = (bid >> 3) * 2 + (bid & 1);
    const int node  = seq * 4 + wave;
    const bool valid = node < N;
    if (!POOL && !valid) return;
    const int cw = valid ? node : N - 1;          // clamped (POOL: harmless work)

    const int lo = rowptr[cw], hi = rowptr[cw + 1];
    const float dd = dinv[cw];

    const int eg  = lane >> 2;                    // edge slot 0..15
    const int sub = lane & 3;                     // 8-dim block within slice
    const int dbase = slice * 32 + sub * 8;       // ushort offset in row

    float a[8];
    {   // self term (count once: slot 0 only)
        bf16x8 sv = *(const bf16x8*)(hb + ((size_t)cw << 7) + dbase);
#pragma unroll
        for (int d = 0; d < 8; ++d) a[d] = (eg == 0) ? bf2f(sv[d]) : 0.f;
    }

    const ushort* hsl = hb + dbase;

    for (int base = lo; base < hi; base += 64) {
        int cnt = min(64, hi - base);
        int sidx = (int)csr[base + (lane < cnt ? lane : cnt - 1)];  // coalesced chunk
        int j = 0;
        for (; j + 32 <= cnt; j += 32) {          // 2 loads in flight, 32 edges
            int s0 = __shfl(sidx, j + eg, 64);
            int s1 = __shfl(sidx, j + 16 + eg, 64);
            bf16x8 p0 = *(const bf16x8*)(hsl + ((size_t)s0 << 7));
            bf16x8 p1 = *(const bf16x8*)(hsl + ((size_t)s1 << 7));
#pragma unroll
            for (int d = 0; d < 8; ++d) a[d] += bf2f(p0[d]);
#pragma unroll
            for (int d = 0; d < 8; ++d) a[d] += bf2f(p1[d]);
        }
        if (j < cnt) {                            // predicated tail (<=31 edges)
            int rem = cnt - j;
            int e0 = j + eg;
            int s0 = __shfl(sidx, e0 < cnt ? e0 : cnt - 1, 64);
            bf16x8 p0 = *(const bf16x8*)(hsl + ((size_t)s0 << 7));
            if (rem > 16) {                       // wave-uniform branch
                int e1 = j + 16 + eg;
                int s1 = __shfl(sidx, e1 < cnt ? e1 : cnt - 1, 64);
                bf16x8 p1 = *(const bf16x8*)(hsl + ((size_t)s1 << 7));
                bool v1 = e1 < cnt;
#pragma unroll
                for (int d = 0; d < 8; ++d) a[d] += v1 ? bf2f(p1[d]) : 0.f;
            }
            bool v0 = e0 < cnt;
#pragma unroll
            for (int d = 0; d < 8; ++d) a[d] += v0 ? bf2f(p0[d]) : 0.f;
        }
    }

    // reduce across the 16 edge slots (lanes sub, sub+4, ..., sub+60)
#pragma unroll
    for (int d = 0; d < 8; ++d) {
        a[d] += __shfl_xor(a[d], 4, 64);
        a[d] += __shfl_xor(a[d], 8, 64);
        a[d] += __shfl_xor(a[d], 16, 64);
        a[d] += __shfl_xor(a[d], 32, 64);
        a[d] *= dd;
    }

    if (!POOL) {
        if (eg == 0) {
            bf16x8 o;
#pragma unroll
            for (int d = 0; d < 8; ++d) o[d] = f2bf(a[d]);
            *(bf16x8*)&oh[(size_t)node * 128 + dbase] = o;
        }
        return;
    }

    // POOL path: bias + relu, stash slice row in LDS, block-reduce by graph.
    {
        float4 b0 = ((const float4*)bias)[slice * 8 + sub * 2];
        float4 b1 = ((const float4*)bias)[slice * 8 + sub * 2 + 1];
        a[0] = fmaxf(a[0] + b0.x, 0.f); a[1] = fmaxf(a[1] + b0.y, 0.f);
        a[2] = fmaxf(a[2] + b0.z, 0.f); a[3] = fmaxf(a[3] + b0.w, 0.f);
        a[4] = fmaxf(a[4] + b1.x, 0.f); a[5] = fmaxf(a[5] + b1.y, 0.f);
        a[6] = fmaxf(a[6] + b1.z, 0.f); a[7] = fmaxf(a[7] + b1.w, 0.f);
    }
    if (lane == 0) sgid[wave] = valid ? batch[node] : -1;
    if (eg == 0) {
#pragma unroll
        for (int d = 0; d < 8; ++d) pacc[wave][sub * 8 + d] = a[d];
    }
    __syncthreads();
    if (tid < 32 && sgid[0] >= 0) {
        int c = tid;
        int cur = sgid[0];
        float run = 0.f;
#pragma unroll
        for (int w = 0; w < 4; ++w) {
            int gi = sgid[w];
            if (gi < 0) break;       // tail-block invalid waves (sorted at end)
            if (gi != cur) { atomicAdd(&pool[cur * HID2 + slice * 32 + c], run); run = 0.f; cur = gi; }
            run += pacc[w][c];
        }
        atomicAdd(&pool[cur * HID2 + slice * 32 + c], run);
    }
}

// ---------------- fc ----------------

__device__ __forceinline__ int lower_bound_i(const int* __restrict__ a, int n, int key) {
    int lo = 0, hi = n;
    while (lo < hi) {
        int mid = (lo + hi) >> 1;
        if (a[mid] < key) lo = mid + 1; else hi = mid;
    }
    return lo;
}

__global__ void fc_kernel(const float* __restrict__ pool, const int* __restrict__ batch,
                          const float* __restrict__ Wfc, const float* __restrict__ bfc,
                          float* __restrict__ out, int N) {
    int t = threadIdx.x;  // 256 = 64 graphs * 4 outputs
    int g = t >> 2, o = t & 3;
    int lo = lower_bound_i(batch, N, g);
    int hi = lower_bound_i(batch, N, g + 1);
    float acc = 0.f;
#pragma unroll 8
    for (int c = 0; c < HID2; ++c)
        acc = fmaf(pool[g * HID2 + c], Wfc[c * OUT_DIM + o], acc);
    float inv = 1.0f / fmaxf((float)(hi - lo), 1.0f);
    out[g * OUT_DIM + o] = acc * inv + bfc[o];
}

extern "C" void kernel_launch(void* const* d_in, const int* in_sizes, int n_in,
                              void* d_out, int out_size, void* d_ws, size_t ws_size,
                              hipStream_t stream) {
    const float* x   = (const float*)d_in[0];
    const int* src   = (const int*)d_in[1];
    const int* dst   = (const int*)d_in[2];
    const int* batch = (const int*)d_in[3];
    const float* W1  = (const float*)d_in[4];
    const float* b1  = (const float*)d_in[5];
    const float* W2  = (const float*)d_in[6];
    const float* b2  = (const float*)d_in[7];
    const float* Wfc = (const float*)d_in[8];
    const float* bfc = (const float*)d_in[9];
    float* out = (float*)d_out;

    const int N = in_sizes[0] / IN_DIM;  // 50000
    const int E = in_sizes[1];           // 640000
    const int NB = (N + 255) / 256;      // scan blocks (196)
    const int GA = ((N + 7) / 8) * 8;    // agg grid: 8 XCD lanes x ceil(N/8)

    // ---- workspace layout (~50 MB; region aliasing) ----
    char* ws = (char*)d_ws;
    size_t off = 0;
    auto alloc = [&](size_t bytes) {
        char* p = ws + off;
        off = (off + bytes + 255) & ~(size_t)255;
        return p;
    };
    float*  dinv   = (float*) alloc((size_t)N * 4);
    int*    count  = (int*)   alloc((size_t)N * 4);
    int*    rowptr = (int*)   alloc((size_t)(N + 1) * 4);
    int*    bsums  = (int*)   alloc(256 * 4);
    ushort* rank   = (ushort*)alloc((size_t)E * 2);
    ushort* csr    = (ushort*)alloc((size_t)E * 2);
    short*  W1th   = (short*) alloc((size_t)IN_DIM * HID * 2);
    short*  W1tl   = (short*) alloc((size_t)IN_DIM * HID * 2);
    short*  W2th   = (short*) alloc((size_t)HID * HID2 * 2);
    short*  W2tl   = (short*) alloc((size_t)HID * HID2 * 2);
    // region Z (12.8 MB): xb -> later h2b (bf16)
    ushort* xb     = (ushort*)alloc((size_t)N * IN_DIM * 2);
    // region X (12.8 MB): axb (bf16, agg1 out)
    short*  axb    = (short*) alloc((size_t)N * IN_DIM * 2);
    // a1 hi-only (25.6 MB)
    short*  a1h    = (short*) alloc((size_t)N * HID * 2);
    float*  pool   = (float*) alloc((size_t)NGRAPH * HID2 * 4);
    ushort* h2b = xb;              // xb dead after agg1

    // ---- weight prep + count zero + pool zero ----
    wprep_all_kernel<<<(max(IN_DIM * HID, N) + 255) / 256, 256, 0, stream>>>(
        W1, W1th, W1tl, W2, W2th, W2tl, count, pool, N);

    // ---- CSR build (once; serves both layers) ----
    hist_kernel<<<(E + 255) / 256, 256, 0, stream>>>(dst, count, rank, E);
    scan1_kernel<<<NB, 256, 0, stream>>>(count, bsums, N);
    scan3_kernel<<<NB, 256, 0, stream>>>(count, bsums, rowptr, dinv, N, E, NB);
    scatter_scale_kernel<<<(N * 64 + 255) / 256, 256, 0, stream>>>(
        src, dst, rank, rowptr, csr, x, dinv, xb, E, N * 64);

    // ---- layer 1 ----
    agg_slice_kernel<false><<<GA, 256, 0, stream>>>(
        xb, dinv, rowptr, csr, nullptr, axb, nullptr, nullptr, N);
    gemm_tile_kernel<IN_DIM, HID, false, true, false>
        <<<dim3(HID / 128, (N + 127) / 128), 256, 0, stream>>>(
        axb, nullptr, W1th, W1tl, b1, nullptr, a1h, N);

    // ---- layer 2 ----
    gemm_tile_kernel<HID, HID2, false, false, true>
        <<<dim3(HID2 / 128, (N + 127) / 128), 256, 0, stream>>>(
        a1h, nullptr, W2th, W2tl, nullptr, dinv, (short*)h2b, N);
    agg_slice_kernel<true><<<GA, 256, 0, stream>>>(
        h2b, dinv, rowptr, csr, b2, nullptr, batch, pool, N);

    // ---- fc ----
    fc_kernel<<<1, NGRAPH * OUT_DIM, 0, stream>>>(pool, batch, Wfc, bfc, out, N);
}

// Round 5
// 242.662 us; speedup vs baseline: 1.4258x; 1.4258x over previous
//
#include <hip/hip_runtime.h>

// GCN forward. All inter-kernel feature traffic in bf16.
//   xb  = bf16(x * dinv_row)                       (fused into scatter)
//   axb = bf16(dd*(Σ_{s} xb[s] + xb[d]))           (agg1, bf16 out)
//   a1  = relu(axb@W1 + b1)                        (MFMA GEMM, bf16 out)
//   h2b = bf16((a1@W2) * dinv_row)                 (MFMA GEMM, bf16 out)
//   agg2+pool: pool[g] += relu(dd*(Σ h2b[s] + h2b[d]) + b2)   (fused, no a2b)
//   out = pool/cnt @ Wfc + bfc
// R20: REVERT r19's XCD slicing (346us: locality never materialized — 80MB
// L2-miss traffic — while MLP collapsed to 2 and wave count x4). Key r19
// lesson: less miss traffic but 2x slower => agg is LATENCY/MLP-bound, not
// BW-bound. This round: group-per-node agg — each 16-lane group owns one node
// (4 nodes/wave, 16/block). 16 clamped 16B gathers issued per 16-edge chunk
// before accumulation => 32-64 independent loads in flight per wave (vs ~8).
// No cross-group reduce; 256B contiguous writes per group. N%16==0: no tail.
// R17 (kept): pool fused into agg2 (no a2b); scan2 folded into scan3.

constexpr int IN_DIM  = 128;
constexpr int HID     = 256;
constexpr int HID2    = 128;
constexpr int OUT_DIM = 4;
constexpr int NGRAPH  = 64;
constexpr int TP      = 132;  // epilogue LDS tile pitch (shorts)

typedef __attribute__((ext_vector_type(8))) short bf16x8;
typedef __attribute__((ext_vector_type(4))) float f32x4;

__device__ __forceinline__ short f2bf(float f) {
    union { float f; unsigned u; } v; v.f = f;
    unsigned r = v.u + 0x7fff + ((v.u >> 16) & 1);   // RNE
    return (short)(r >> 16);
}
__device__ __forceinline__ float bf2f(short s) {
    union { unsigned u; float f; } v; v.u = ((unsigned)(unsigned short)s) << 16;
    return v.f;
}

// ---------------- W prep (both layers) + count zero + pool zero ----------------

__global__ void wprep_all_kernel(const float* __restrict__ W1, short* __restrict__ W1th,
                                 short* __restrict__ W1tl,
                                 const float* __restrict__ W2, short* __restrict__ W2th,
                                 short* __restrict__ W2tl,
                                 int* __restrict__ count, float* __restrict__ pool, int N) {
    int i = blockIdx.x * blockDim.x + threadIdx.x;
    if (i < IN_DIM * HID) {
        int k = i / HID, n = i % HID;
        float w = W1[i];
        short h = f2bf(w);
        W1th[n * IN_DIM + k] = h;
        W1tl[n * IN_DIM + k] = f2bf(w - bf2f(h));
    }
    if (i < HID * HID2) {
        int k = i / HID2, n = i % HID2;
        float w = W2[i];
        short h = f2bf(w);
        W2th[n * HID + k] = h;
        W2tl[n * HID + k] = f2bf(w - bf2f(h));
    }
    if (i < N) count[i] = 0;
    if (i < NGRAPH * HID2) pool[i] = 0.f;
}

// ---------------- CSR build ----------------
// hist: count in-degree AND record each edge's rank within its dst row.

__global__ void hist_kernel(const int* __restrict__ dst, int* __restrict__ count,
                            ushort* __restrict__ rank, int E) {
    int i = blockIdx.x * blockDim.x + threadIdx.x;
    if (i < E) rank[i] = (ushort)atomicAdd(&count[dst[i]], 1);
}

__global__ void scan1_kernel(const int* __restrict__ count, int* __restrict__ bsums, int N) {
    __shared__ int s[256];
    int t = threadIdx.x, i = blockIdx.x * 256 + t;
    int v = (i < N) ? count[i] : 0;
    s[t] = v; __syncthreads();
    for (int o = 1; o < 256; o <<= 1) {
        int x = (t >= o) ? s[t - o] : 0;
        __syncthreads(); s[t] += x; __syncthreads();
    }
    if (t == 255) bsums[blockIdx.x] = s[255];
}

// scan3: inline-scan the (<=256) raw block sums, then per-element scan of count.
__global__ void scan3_kernel(const int* __restrict__ count, const int* __restrict__ bsums,
                             int* __restrict__ rowptr, float* __restrict__ dinv,
                             int N, int E, int nb) {
    __shared__ int sb[256];
    __shared__ int s[256];
    int t = threadIdx.x, i = blockIdx.x * 256 + t;
    // inclusive scan of raw bsums
    int bv = (t < nb) ? bsums[t] : 0;
    sb[t] = bv; __syncthreads();
    for (int o = 1; o < 256; o <<= 1) {
        int x = (t >= o) ? sb[t - o] : 0;
        __syncthreads(); sb[t] += x; __syncthreads();
    }
    // exclusive prefix for this block (LDS broadcast read)
    int myex = (blockIdx.x == 0) ? 0 : sb[blockIdx.x - 1];
    // per-element scan of count
    int v = (i < N) ? count[i] : 0;
    s[t] = v; __syncthreads();
    for (int o = 1; o < 256; o <<= 1) {
        int x = (t >= o) ? s[t - o] : 0;
        __syncthreads(); s[t] += x; __syncthreads();
    }
    if (i < N) {
        rowptr[i] = myex + s[t] - v;
        dinv[i] = rsqrtf((float)v + 1.0f);
        if (i == 0) rowptr[N] = E;
    }
}

// scatter (no atomics: p = rowptr[dst]+rank) + xb = bf16(x * dinv_row)
__global__ void scatter_scale_kernel(const int* __restrict__ src, const int* __restrict__ dst,
                                     const ushort* __restrict__ rank,
                                     const int* __restrict__ rowptr, ushort* __restrict__ csr,
                                     const float* __restrict__ x, const float* __restrict__ dinv,
                                     ushort* __restrict__ xb, int E, int total2) {
    int i = blockIdx.x * blockDim.x + threadIdx.x;
    if (i < E) {
        int p = rowptr[dst[i]] + (int)rank[i];
        csr[p] = (ushort)src[i];
    }
    if (i < total2) {
        float d = dinv[i >> 6];
        float2 v = ((const float2*)x)[i];
        ushort2 o;
        o.x = (ushort)f2bf(v.x * d);
        o.y = (ushort)f2bf(v.y * d);
        ((ushort2*)xb)[i] = o;
    }
}

// ---------------- split-bf16 LDS-tiled MFMA GEMM, bf16 output ----------------
// Cb[M,N] = post( (Ah[+Al]) @ (Bh+Bl)^T ), B given N x K (transposed).
// Block: 128x128 tile, 256 thr. ALO: A has a lo plane (3 MFMAs) else 2 MFMAs.
// LDS slab = 16x32 tile in MFMA fragment order; single ds_read_b128 per frag.
// C/D layout (16x16x32): col=lane&15, row=(lane>>4)*4+reg [verified m89/m91].
// Epilogue: acc -> padded LDS bf16 tile (pitch TP=132) -> coalesced 16B stores.
// RELU: v=relu(v+bias[col]).  SCALED: v*=dinv[row] (pre-scale for gather table).

template <int K, int N, bool ALO, bool RELU, bool SCALED>
__launch_bounds__(256)
__global__ void gemm_tile_kernel(const short* __restrict__ Ah, const short* __restrict__ Al,
                                 const short* __restrict__ Bh, const short* __restrict__ Bl,
                                 const float* __restrict__ bias,
                                 const float* __restrict__ dinv,
                                 short* __restrict__ Cb, int M) {
    __shared__ __align__(16) short LDSBUF[128 * TP];     // 33792 B >= 32 KB staging
    short (*S)[8][512] = (short (*)[8][512])LDSBUF;      // staging view [4][8][512]

    const int tid  = threadIdx.x;
    const int wave = tid >> 6;
    const int lane = tid & 63;
    const int row0 = blockIdx.y * 128;
    const int col0 = blockIdx.x * 128;

    const int l15 = lane & 15;
    const int kq  = (lane >> 4) * 8;

    f32x4 acc[4][4];
#pragma unroll
    for (int i = 0; i < 4; ++i)
#pragma unroll
        for (int j = 0; j < 4; ++j) acc[i][j] = f32x4{0.f, 0.f, 0.f, 0.f};

    const int mt0 = (wave & 1) * 4;
    const int nt0 = (wave >> 1) * 4;

    for (int kb = 0; kb < K; kb += 32) {
        // ---- staging: constant-bound loops only ----
        if (ALO) {
            const short* gsrc = (wave == 0) ? Ah : (wave == 1) ? Al : (wave == 2) ? Bh : Bl;
            const bool isA = wave < 2;
            const int rb = (isA ? row0 : col0) + l15;
            bf16x8 stg[8];
#pragma unroll
            for (int j = 0; j < 8; ++j) {
                int rr = rb + j * 16;
                if (isA && rr >= M) rr = M - 1;       // clamp tail rows (stores guarded)
                stg[j] = *(const bf16x8*)(gsrc + (size_t)rr * K + kb + kq);
            }
#pragma unroll
            for (int j = 0; j < 8; ++j)
                *(bf16x8*)&S[wave][j][lane * 8] = stg[j];
        } else {
            if (wave < 2) {
                const int rb = row0 + l15;
                bf16x8 stg[4];
#pragma unroll
                for (int j = 0; j < 4; ++j) {
                    int rr = rb + (wave * 4 + j) * 16;
                    if (rr >= M) rr = M - 1;
                    stg[j] = *(const bf16x8*)(Ah + (size_t)rr * K + kb + kq);
                }
#pragma unroll
                for (int j = 0; j < 4; ++j)
                    *(bf16x8*)&S[0][wave * 4 + j][lane * 8] = stg[j];
            } else {
                const short* gsrc = (wave == 2) ? Bh : Bl;
                const int rb = col0 + l15;
                bf16x8 stg[8];
#pragma unroll
                for (int j = 0; j < 8; ++j)
                    stg[j] = *(const bf16x8*)(gsrc + (size_t)(rb + j * 16) * K + kb + kq);
#pragma unroll
                for (int j = 0; j < 8; ++j)
                    *(bf16x8*)&S[wave][j][lane * 8] = stg[j];
            }
        }
        __syncthreads();

        bf16x8 ah[4], al[4], bh[4], bl[4];
#pragma unroll
        for (int i = 0; i < 4; ++i) {
            ah[i] = *(const bf16x8*)&S[0][mt0 + i][lane * 8];
            if (ALO) al[i] = *(const bf16x8*)&S[1][mt0 + i][lane * 8];
            bh[i] = *(const bf16x8*)&S[2][nt0 + i][lane * 8];
            bl[i] = *(const bf16x8*)&S[3][nt0 + i][lane * 8];
        }
#pragma unroll
        for (int i = 0; i < 4; ++i)
#pragma unroll
            for (int j = 0; j < 4; ++j) {
                acc[i][j] = __builtin_amdgcn_mfma_f32_16x16x32_bf16(ah[i], bh[j], acc[i][j], 0, 0, 0);
                acc[i][j] = __builtin_amdgcn_mfma_f32_16x16x32_bf16(ah[i], bl[j], acc[i][j], 0, 0, 0);
                if (ALO)
                    acc[i][j] = __builtin_amdgcn_mfma_f32_16x16x32_bf16(al[i], bh[j], acc[i][j], 0, 0, 0);
            }
        __syncthreads();
    }

    // ---- epilogue: acc -> padded LDS bf16 tile -> coalesced stores ----
    short* T = LDSBUF;                      // 128 x TP shorts
    const int lrow_b = (wave & 1) * 64 + (lane >> 4) * 4;
    const int lcol_b = (wave >> 1) * 64 + l15;
#pragma unroll
    for (int j = 0; j < 4; ++j) {
        int lcol = lcol_b + j * 16;
        float bv = RELU ? bias[col0 + lcol] : 0.f;
#pragma unroll
        for (int i = 0; i < 4; ++i) {
#pragma unroll
            for (int r = 0; r < 4; ++r) {
                int lrow = lrow_b + i * 16 + r;
                float v = acc[i][j][r];
                if (RELU) v = fmaxf(v + bv, 0.f);
                if (SCALED) {
                    int dr = row0 + lrow; if (dr >= M) dr = M - 1;
                    v *= dinv[dr];
                }
                T[lrow * TP + lcol] = f2bf(v);
            }
        }
    }
    __syncthreads();
#pragma unroll
    for (int it = 0; it < 8; ++it) {
        int chunk = it * 256 + tid;          // 2048 chunks of 8 shorts
        int lr = chunk >> 4;
        int lc = (chunk & 15) * 8;
        int grow = row0 + lr;
        if (grow < M)
            *(bf16x8*)(Cb + (size_t)grow * N + col0 + lc) = *(const bf16x8*)&T[lr * TP + lc];
    }
}

// ---------------- group-per-node bf16 gather aggregation (D=128) ----------------
// One 16-lane group per dst node: 4 nodes/wave, 16 nodes/block (256 thr).
// Lane li holds dims [li*8, li*8+8) (16B). Per 16-edge chunk: group loads 16
// csr indices (coalesced 32B), then issues 16 clamped 16B gathers (2 batches
// of 8, both issued before accumulation) -> 32-64 independent loads in flight
// per wave. Accumulation predicated on e<cnt; clamped dupes are L1 hits.
// r = dd * (Σ_{s in row} hb[s] + hb[node]); hb pre-scaled by dinv[src].
// !POOL: group writes 256B contiguous row. POOL: bias+relu then 16-node LDS
// block-reduce by graph run -> atomicAdd into pool (a2b never materialized).

template <bool POOL>
__launch_bounds__(256)
__global__ void agg_group_kernel(const ushort* __restrict__ hb, const float* __restrict__ dinv,
                                 const int* __restrict__ rowptr, const ushort* __restrict__ csr,
                                 const float* __restrict__ bias,
                                 short* __restrict__ oh,
                                 const int* __restrict__ batch, float* __restrict__ pool,
                                 int N) {
    __shared__ float pacc[16][128];
    __shared__ int   sgid[16];

    const int tid  = threadIdx.x;
    const int li   = tid & 15;           // dim slot within group
    const int nib  = tid >> 4;           // node-in-block 0..15
    const int node = blockIdx.x * 16 + nib;
    const bool valid = node < N;         // N%16==0 -> always true, kept for safety
    const int cw = valid ? node : N - 1;

    const int lo = rowptr[cw], hi = rowptr[cw + 1];
    const float dd = dinv[cw];

    float a[8];
    {   // self term
        bf16x8 sv = *(const bf16x8*)(hb + ((size_t)cw << 7) + (li << 3));
#pragma unroll
        for (int d = 0; d < 8; ++d) a[d] = bf2f(sv[d]);
    }

    const ushort* hsl = hb + (li << 3);

    for (int base = lo; base < hi; base += 16) {
        int cnt = min(16, hi - base);
        int sidx = (int)csr[base + (li < cnt ? li : cnt - 1)];   // 32B/group, coalesced
        bf16x8 p[8], q[8];
#pragma unroll
        for (int u = 0; u < 8; ++u) {                            // batch 1: edges 0..7
            int s = __shfl(sidx, u < cnt ? u : cnt - 1, 16);
            p[u] = *(const bf16x8*)(hsl + ((size_t)s << 7));
        }
#pragma unroll
        for (int u = 0; u < 8; ++u) {                            // batch 2: edges 8..15
            int e = 8 + u;
            int s = __shfl(sidx, e < cnt ? e : cnt - 1, 16);
            q[u] = *(const bf16x8*)(hsl + ((size_t)s << 7));
        }
#pragma unroll
        for (int u = 0; u < 8; ++u) {
            bool v = u < cnt;
#pragma unroll
            for (int d = 0; d < 8; ++d) a[d] += v ? bf2f(p[u][d]) : 0.f;
        }
#pragma unroll
        for (int u = 0; u < 8; ++u) {
            bool v = 8 + u < cnt;
#pragma unroll
            for (int d = 0; d < 8; ++d) a[d] += v ? bf2f(q[u][d]) : 0.f;
        }
    }

#pragma unroll
    for (int d = 0; d < 8; ++d) a[d] *= dd;

    if (!POOL) {
        if (valid) {
            bf16x8 o;
#pragma unroll
            for (int d = 0; d < 8; ++d) o[d] = f2bf(a[d]);
            *(bf16x8*)&oh[(size_t)node * 128 + li * 8] = o;   // 256B/group contiguous
        }
        return;
    }

    // POOL path: bias + relu, stash node row in LDS, block-reduce by graph run.
    {
        float4 b0 = ((const float4*)bias)[li * 2];
        float4 b1 = ((const float4*)bias)[li * 2 + 1];
        a[0] = fmaxf(a[0] + b0.x, 0.f); a[1] = fmaxf(a[1] + b0.y, 0.f);
        a[2] = fmaxf(a[2] + b0.z, 0.f); a[3] = fmaxf(a[3] + b0.w, 0.f);
        a[4] = fmaxf(a[4] + b1.x, 0.f); a[5] = fmaxf(a[5] + b1.y, 0.f);
        a[6] = fmaxf(a[6] + b1.z, 0.f); a[7] = fmaxf(a[7] + b1.w, 0.f);
    }
    if (li == 0) sgid[nib] = valid ? batch[node] : -1;
#pragma unroll
    for (int d = 0; d < 8; ++d) pacc[nib][li * 8 + d] = a[d];
    __syncthreads();
    if (tid < 128) {
        int c = tid;
        int cur = sgid[0];               // first node of block always valid
        float run = 0.f;
#pragma unroll 1
        for (int w = 0; w < 16; ++w) {
            int gi = sgid[w];
            if (gi < 0) break;           // tail-block invalid nodes (trailing)
            if (gi != cur) { atomicAdd(&pool[cur * HID2 + c], run); run = 0.f; cur = gi; }
            run += pacc[w][c];
        }
        atomicAdd(&pool[cur * HID2 + c], run);
    }
}

// ---------------- fc ----------------

__device__ __forceinline__ int lower_bound_i(const int* __restrict__ a, int n, int key) {
    int lo = 0, hi = n;
    while (lo < hi) {
        int mid = (lo + hi) >> 1;
        if (a[mid] < key) lo = mid + 1; else hi = mid;
    }
    return lo;
}

__global__ void fc_kernel(const float* __restrict__ pool, const int* __restrict__ batch,
                          const float* __restrict__ Wfc, const float* __restrict__ bfc,
                          float* __restrict__ out, int N) {
    int t = threadIdx.x;  // 256 = 64 graphs * 4 outputs
    int g = t >> 2, o = t & 3;
    int lo = lower_bound_i(batch, N, g);
    int hi = lower_bound_i(batch, N, g + 1);
    float acc = 0.f;
#pragma unroll 8
    for (int c = 0; c < HID2; ++c)
        acc = fmaf(pool[g * HID2 + c], Wfc[c * OUT_DIM + o], acc);
    float inv = 1.0f / fmaxf((float)(hi - lo), 1.0f);
    out[g * OUT_DIM + o] = acc * inv + bfc[o];
}

extern "C" void kernel_launch(void* const* d_in, const int* in_sizes, int n_in,
                              void* d_out, int out_size, void* d_ws, size_t ws_size,
                              hipStream_t stream) {
    const float* x   = (const float*)d_in[0];
    const int* src   = (const int*)d_in[1];
    const int* dst   = (const int*)d_in[2];
    const int* batch = (const int*)d_in[3];
    const float* W1  = (const float*)d_in[4];
    const float* b1  = (const float*)d_in[5];
    const float* W2  = (const float*)d_in[6];
    const float* b2  = (const float*)d_in[7];
    const float* Wfc = (const float*)d_in[8];
    const float* bfc = (const float*)d_in[9];
    float* out = (float*)d_out;

    const int N = in_sizes[0] / IN_DIM;  // 50000
    const int E = in_sizes[1];           // 640000
    const int NB = (N + 255) / 256;      // scan blocks (196)
    const int GA = (N + 15) / 16;        // agg blocks (3125; 16 nodes each)

    // ---- workspace layout (~50 MB; region aliasing) ----
    char* ws = (char*)d_ws;
    size_t off = 0;
    auto alloc = [&](size_t bytes) {
        char* p = ws + off;
        off = (off + bytes + 255) & ~(size_t)255;
        return p;
    };
    float*  dinv   = (float*) alloc((size_t)N * 4);
    int*    count  = (int*)   alloc((size_t)N * 4);
    int*    rowptr = (int*)   alloc((size_t)(N + 1) * 4);
    int*    bsums  = (int*)   alloc(256 * 4);
    ushort* rank   = (ushort*)alloc((size_t)E * 2);
    ushort* csr    = (ushort*)alloc((size_t)E * 2);
    short*  W1th   = (short*) alloc((size_t)IN_DIM * HID * 2);
    short*  W1tl   = (short*) alloc((size_t)IN_DIM * HID * 2);
    short*  W2th   = (short*) alloc((size_t)HID * HID2 * 2);
    short*  W2tl   = (short*) alloc((size_t)HID * HID2 * 2);
    // region Z (12.8 MB): xb -> later h2b (bf16)
    ushort* xb     = (ushort*)alloc((size_t)N * IN_DIM * 2);
    // region X (12.8 MB): axb (bf16, agg1 out)
    short*  axb    = (short*) alloc((size_t)N * IN_DIM * 2);
    // a1 hi-only (25.6 MB)
    short*  a1h    = (short*) alloc((size_t)N * HID * 2);
    float*  pool   = (float*) alloc((size_t)NGRAPH * HID2 * 4);
    ushort* h2b = xb;              // xb dead after agg1

    // ---- weight prep + count zero + pool zero ----
    wprep_all_kernel<<<(max(IN_DIM * HID, N) + 255) / 256, 256, 0, stream>>>(
        W1, W1th, W1tl, W2, W2th, W2tl, count, pool, N);

    // ---- CSR build (once; serves both layers) ----
    hist_kernel<<<(E + 255) / 256, 256, 0, stream>>>(dst, count, rank, E);
    scan1_kernel<<<NB, 256, 0, stream>>>(count, bsums, N);
    scan3_kernel<<<NB, 256, 0, stream>>>(count, bsums, rowptr, dinv, N, E, NB);
    scatter_scale_kernel<<<(N * 64 + 255) / 256, 256, 0, stream>>>(
        src, dst, rank, rowptr, csr, x, dinv, xb, E, N * 64);

    // ---- layer 1 ----
    agg_group_kernel<false><<<GA, 256, 0, stream>>>(
        xb, dinv, rowptr, csr, nullptr, axb, nullptr, nullptr, N);
    gemm_tile_kernel<IN_DIM, HID, false, true, false>
        <<<dim3(HID / 128, (N + 127) / 128), 256, 0, stream>>>(
        axb, nullptr, W1th, W1tl, b1, nullptr, a1h, N);

    // ---- layer 2 ----
    gemm_tile_kernel<HID, HID2, false, false, true>
        <<<dim3(HID2 / 128, (N + 127) / 128), 256, 0, stream>>>(
        a1h, nullptr, W2th, W2tl, nullptr, dinv, (short*)h2b, N);
    agg_group_kernel<true><<<GA, 256, 0, stream>>>(
        h2b, dinv, rowptr, csr, b2, nullptr, batch, pool, N);

    // ---- fc ----
    fc_kernel<<<1, NGRAPH * OUT_DIM, 0, stream>>>(pool, batch, Wfc, bfc, out, N);
}

// Round 6
// 240.024 us; speedup vs baseline: 1.4415x; 1.0110x over previous
//
#include <hip/hip_runtime.h>

// GCN forward. All inter-kernel feature traffic in bf16.
//   xb  = bf16(x * dinv_row)                       (fused into scatter)
//   axb = bf16(dd*(Σ_{s} xb[s] + xb[d]))           (agg1, bf16 out)
//   fused MLP: a1 = relu(axb@W1+b1) [LDS only] ; h2b = bf16((a1@W2)*dinv)
//   agg2+pool: pool[g] += relu(dd*(Σ h2b[s] + h2b[d]) + b2)   (fused, no a2b)
//   out = pool/cnt @ Wfc + bfc
// R21: GEMM1+GEMM2 fused into one barrier-free-K-loop kernel (mlp_fused):
//  - a1h buffer eliminated (25.6 MB write + 25.6 MB read + 1 dispatch).
//  - A (axb) staged ONCE for all K (16 KB); B (weights) read as direct global
//    fragments (L2-hot, zero LDS reuse existed anyway) -> NO barrier in K-loops
//    (old structure: 2 barriers/K-step with only 4-8 steps).
//  - phase1 acc -> in-LDS transpose (C/D layout -> A-frag layout) -> phase2.
//  - 64-row M-tiles: 782 blocks (vs GEMM2's old 391 = 1.5/CU imbalance).
//  - numerics bit-identical (same bf16 quantization points, same K order).
// R20 (kept): group-per-node agg, 16 nodes/block, MLP-maximized gathers.
// R17 (kept): pool fused into agg2; scan2 folded into scan3. 9 dispatches.

constexpr int IN_DIM  = 128;
constexpr int HID     = 256;
constexpr int HID2    = 128;
constexpr int OUT_DIM = 4;
constexpr int NGRAPH  = 64;

typedef __attribute__((ext_vector_type(8))) short bf16x8;
typedef __attribute__((ext_vector_type(4))) float f32x4;

__device__ __forceinline__ short f2bf(float f) {
    union { float f; unsigned u; } v; v.f = f;
    unsigned r = v.u + 0x7fff + ((v.u >> 16) & 1);   // RNE
    return (short)(r >> 16);
}
__device__ __forceinline__ float bf2f(short s) {
    union { unsigned u; float f; } v; v.u = ((unsigned)(unsigned short)s) << 16;
    return v.f;
}

// ---------------- W prep (both layers) + count zero + pool zero ----------------

__global__ void wprep_all_kernel(const float* __restrict__ W1, short* __restrict__ W1th,
                                 short* __restrict__ W1tl,
                                 const float* __restrict__ W2, short* __restrict__ W2th,
                                 short* __restrict__ W2tl,
                                 int* __restrict__ count, float* __restrict__ pool, int N) {
    int i = blockIdx.x * blockDim.x + threadIdx.x;
    if (i < IN_DIM * HID) {
        int k = i / HID, n = i % HID;
        float w = W1[i];
        short h = f2bf(w);
        W1th[n * IN_DIM + k] = h;
        W1tl[n * IN_DIM + k] = f2bf(w - bf2f(h));
    }
    if (i < HID * HID2) {
        int k = i / HID2, n = i % HID2;
        float w = W2[i];
        short h = f2bf(w);
        W2th[n * HID + k] = h;
        W2tl[n * HID + k] = f2bf(w - bf2f(h));
    }
    if (i < N) count[i] = 0;
    if (i < NGRAPH * HID2) pool[i] = 0.f;
}

// ---------------- CSR build ----------------

__global__ void hist_kernel(const int* __restrict__ dst, int* __restrict__ count,
                            ushort* __restrict__ rank, int E) {
    int i = blockIdx.x * blockDim.x + threadIdx.x;
    if (i < E) rank[i] = (ushort)atomicAdd(&count[dst[i]], 1);
}

__global__ void scan1_kernel(const int* __restrict__ count, int* __restrict__ bsums, int N) {
    __shared__ int s[256];
    int t = threadIdx.x, i = blockIdx.x * 256 + t;
    int v = (i < N) ? count[i] : 0;
    s[t] = v; __syncthreads();
    for (int o = 1; o < 256; o <<= 1) {
        int x = (t >= o) ? s[t - o] : 0;
        __syncthreads(); s[t] += x; __syncthreads();
    }
    if (t == 255) bsums[blockIdx.x] = s[255];
}

// scan3: inline-scan the (<=256) raw block sums, then per-element scan of count.
__global__ void scan3_kernel(const int* __restrict__ count, const int* __restrict__ bsums,
                             int* __restrict__ rowptr, float* __restrict__ dinv,
                             int N, int E, int nb) {
    __shared__ int sb[256];
    __shared__ int s[256];
    int t = threadIdx.x, i = blockIdx.x * 256 + t;
    int bv = (t < nb) ? bsums[t] : 0;
    sb[t] = bv; __syncthreads();
    for (int o = 1; o < 256; o <<= 1) {
        int x = (t >= o) ? sb[t - o] : 0;
        __syncthreads(); sb[t] += x; __syncthreads();
    }
    int myex = (blockIdx.x == 0) ? 0 : sb[blockIdx.x - 1];
    int v = (i < N) ? count[i] : 0;
    s[t] = v; __syncthreads();
    for (int o = 1; o < 256; o <<= 1) {
        int x = (t >= o) ? s[t - o] : 0;
        __syncthreads(); s[t] += x; __syncthreads();
    }
    if (i < N) {
        rowptr[i] = myex + s[t] - v;
        dinv[i] = rsqrtf((float)v + 1.0f);
        if (i == 0) rowptr[N] = E;
    }
}

// scatter (no atomics: p = rowptr[dst]+rank) + xb = bf16(x * dinv_row)
__global__ void scatter_scale_kernel(const int* __restrict__ src, const int* __restrict__ dst,
                                     const ushort* __restrict__ rank,
                                     const int* __restrict__ rowptr, ushort* __restrict__ csr,
                                     const float* __restrict__ x, const float* __restrict__ dinv,
                                     ushort* __restrict__ xb, int E, int total2) {
    int i = blockIdx.x * blockDim.x + threadIdx.x;
    if (i < E) {
        int p = rowptr[dst[i]] + (int)rank[i];
        csr[p] = (ushort)src[i];
    }
    if (i < total2) {
        float d = dinv[i >> 6];
        float2 v = ((const float2*)x)[i];
        ushort2 o;
        o.x = (ushort)f2bf(v.x * d);
        o.y = (ushort)f2bf(v.y * d);
        ((ushort2*)xb)[i] = o;
    }
}

// ---------------- fused MLP: h2b = bf16((relu(axb@W1+b1)@W2)*dinv) ----------------
// One block per 64-row M-tile (grid 782), 256 thr = 4 waves; barrier-free K-loops.
// Wave w: phase1 cols w*64..w*64+64 (4m x 4n frags), phase2 cols w*32 (4m x 2n).
// A0: axb tile in MFMA-frag layout, staged once (16 KB). B-frags: direct global
// (L2-hot weights; LDS staging had zero reuse). A1: a1 tile in frag layout
// (32 KB) filled by in-register transpose of phase1 C/D acc:
//   element (r,c) -> frag(r>>4, c>>5), lane (r&15)+16*((c>>3)&3), elem c&7
// (element-verified). OUT tile (64 x pitch 132) overlays A0 (dead after phase1).
// 3 barriers total. Numerics = old gemm1+gemm2 bit-exact (same bf16 points).

__launch_bounds__(256)
__global__ void mlp_fused_kernel(const short* __restrict__ A,
                                 const short* __restrict__ W1h, const short* __restrict__ W1l,
                                 const float* __restrict__ b1,
                                 const short* __restrict__ W2h, const short* __restrict__ W2l,
                                 const float* __restrict__ dinv,
                                 short* __restrict__ Cb, int M) {
    __shared__ __align__(16) short L[16384 + 8448];   // A1 | A0-union-OUT (49.7 KB)
    short* A1 = L;
    short* A0 = L + 16384;
    __shared__ float dinv_s[64];

    const int tid  = threadIdx.x;
    const int w    = tid >> 6;
    const int lane = tid & 63;
    const int l15  = lane & 15;
    const int kq8  = (lane >> 4) * 8;
    const int row0 = blockIdx.x * 64;

    // ---- stage A0 once (wave w -> row-block m=w, all 4 K-steps) ----
    {
        int rr = row0 + w * 16 + l15; if (rr >= M) rr = M - 1;
        const short* ap = A + (size_t)rr * IN_DIM + kq8;
        bf16x8 stg[4];
#pragma unroll
        for (int ks = 0; ks < 4; ++ks) stg[ks] = *(const bf16x8*)(ap + ks * 32);
#pragma unroll
        for (int ks = 0; ks < 4; ++ks) *(bf16x8*)&A0[(w * 4 + ks) * 512 + lane * 8] = stg[ks];
    }
    if (tid < 64) { int r = row0 + tid; dinv_s[tid] = dinv[r < M ? r : M - 1]; }
    __syncthreads();

    // ---- phase 1: a1 = axb @ W1^T (split B), K=128, no barriers ----
    f32x4 acc1[4][4];
#pragma unroll
    for (int m = 0; m < 4; ++m)
#pragma unroll
        for (int n = 0; n < 4; ++n) acc1[m][n] = f32x4{0.f, 0.f, 0.f, 0.f};

    const short* w1hp = W1h + (size_t)(w * 64 + l15) * IN_DIM + kq8;
    const short* w1lp = W1l + (size_t)(w * 64 + l15) * IN_DIM + kq8;
#pragma unroll
    for (int ks = 0; ks < 4; ++ks) {
        bf16x8 af[4], bh[4], bl[4];
#pragma unroll
        for (int m = 0; m < 4; ++m) af[m] = *(const bf16x8*)&A0[(m * 4 + ks) * 512 + lane * 8];
#pragma unroll
        for (int n = 0; n < 4; ++n) {
            bh[n] = *(const bf16x8*)(w1hp + (size_t)(n * 16) * IN_DIM + ks * 32);
            bl[n] = *(const bf16x8*)(w1lp + (size_t)(n * 16) * IN_DIM + ks * 32);
        }
#pragma unroll
        for (int m = 0; m < 4; ++m)
#pragma unroll
            for (int n = 0; n < 4; ++n) {
                acc1[m][n] = __builtin_amdgcn_mfma_f32_16x16x32_bf16(af[m], bh[n], acc1[m][n], 0, 0, 0);
                acc1[m][n] = __builtin_amdgcn_mfma_f32_16x16x32_bf16(af[m], bl[n], acc1[m][n], 0, 0, 0);
            }
    }

    // ---- bias + relu + bf16, transpose-write into A1 frag layout ----
#pragma unroll
    for (int n = 0; n < 4; ++n) {
        int c  = w * 64 + n * 16 + l15;
        float bv = b1[c];
        int ks = c >> 5;
        int q  = (c >> 3) & 3;
        int e  = c & 7;
#pragma unroll
        for (int m = 0; m < 4; ++m)
#pragma unroll
            for (int r4 = 0; r4 < 4; ++r4) {
                int rl = (lane >> 4) * 4 + r4;                 // r & 15
                float v = fmaxf(acc1[m][n][r4] + bv, 0.f);
                A1[(m * 8 + ks) * 512 + (rl + 16 * q) * 8 + e] = f2bf(v);
            }
    }
    __syncthreads();

    // ---- phase 2: h2 = a1 @ W2^T (split B), K=256, no barriers ----
    f32x4 acc2[4][2];
#pragma unroll
    for (int m = 0; m < 4; ++m)
#pragma unroll
        for (int n = 0; n < 2; ++n) acc2[m][n] = f32x4{0.f, 0.f, 0.f, 0.f};

    const short* w2hp = W2h + (size_t)(w * 32 + l15) * HID + kq8;
    const short* w2lp = W2l + (size_t)(w * 32 + l15) * HID + kq8;
#pragma unroll
    for (int ks = 0; ks < 8; ++ks) {
        bf16x8 af[4], bh[2], bl[2];
#pragma unroll
        for (int m = 0; m < 4; ++m) af[m] = *(const bf16x8*)&A1[(m * 8 + ks) * 512 + lane * 8];
#pragma unroll
        for (int n = 0; n < 2; ++n) {
            bh[n] = *(const bf16x8*)(w2hp + (size_t)(n * 16) * HID + ks * 32);
            bl[n] = *(const bf16x8*)(w2lp + (size_t)(n * 16) * HID + ks * 32);
        }
#pragma unroll
        for (int m = 0; m < 4; ++m)
#pragma unroll
            for (int n = 0; n < 2; ++n) {
                acc2[m][n] = __builtin_amdgcn_mfma_f32_16x16x32_bf16(af[m], bh[n], acc2[m][n], 0, 0, 0);
                acc2[m][n] = __builtin_amdgcn_mfma_f32_16x16x32_bf16(af[m], bl[n], acc2[m][n], 0, 0, 0);
            }
    }

    // ---- epilogue: dinv scale -> OUT tile (overlays A0) -> coalesced store ----
    short* T = A0;                                    // 64 x 132 shorts
#pragma unroll
    for (int n = 0; n < 2; ++n) {
        int c = w * 32 + n * 16 + l15;
#pragma unroll
        for (int m = 0; m < 4; ++m)
#pragma unroll
            for (int r4 = 0; r4 < 4; ++r4) {
                int r = m * 16 + (lane >> 4) * 4 + r4;
                T[r * 132 + c] = f2bf(acc2[m][n][r4] * dinv_s[r]);
            }
    }
    __syncthreads();
#pragma unroll
    for (int it = 0; it < 4; ++it) {
        int chunk = it * 256 + tid;                   // 1024 chunks of 8 shorts
        int lr = chunk >> 4;
        int lc = (chunk & 15) * 8;
        int gr = row0 + lr;
        if (gr < M)
            *(bf16x8*)(Cb + (size_t)gr * HID2 + lc) = *(const bf16x8*)&T[lr * 132 + lc];
    }
}

// ---------------- group-per-node bf16 gather aggregation (D=128) ----------------
// One 16-lane group per dst node: 4 nodes/wave, 16 nodes/block (256 thr).
// 16 clamped 16B gathers issued per 16-edge chunk before accumulation
// -> 32-64 independent loads in flight per wave. 256B contiguous writes.
// POOL: bias+relu then 16-node LDS block-reduce by graph run -> atomicAdd.

template <bool POOL>
__launch_bounds__(256)
__global__ void agg_group_kernel(const ushort* __restrict__ hb, const float* __restrict__ dinv,
                                 const int* __restrict__ rowptr, const ushort* __restrict__ csr,
                                 const float* __restrict__ bias,
                                 short* __restrict__ oh,
                                 const int* __restrict__ batch, float* __restrict__ pool,
                                 int N) {
    __shared__ float pacc[16][128];
    __shared__ int   sgid[16];

    const int tid  = threadIdx.x;
    const int li   = tid & 15;
    const int nib  = tid >> 4;
    const int node = blockIdx.x * 16 + nib;
    const bool valid = node < N;
    if (!POOL && !valid) return;
    const int cw = valid ? node : N - 1;

    const int lo = rowptr[cw], hi = rowptr[cw + 1];
    const float dd = dinv[cw];

    float a[8];
    {
        bf16x8 sv = *(const bf16x8*)(hb + ((size_t)cw << 7) + (li << 3));
#pragma unroll
        for (int d = 0; d < 8; ++d) a[d] = bf2f(sv[d]);
    }

    const ushort* hsl = hb + (li << 3);

    for (int base = lo; base < hi; base += 16) {
        int cnt = min(16, hi - base);
        int sidx = (int)csr[base + (li < cnt ? li : cnt - 1)];
        bf16x8 p[8], q[8];
#pragma unroll
        for (int u = 0; u < 8; ++u) {
            int s = __shfl(sidx, u < cnt ? u : cnt - 1, 16);
            p[u] = *(const bf16x8*)(hsl + ((size_t)s << 7));
        }
#pragma unroll
        for (int u = 0; u < 8; ++u) {
            int e = 8 + u;
            int s = __shfl(sidx, e < cnt ? e : cnt - 1, 16);
            q[u] = *(const bf16x8*)(hsl + ((size_t)s << 7));
        }
#pragma unroll
        for (int u = 0; u < 8; ++u) {
            bool v = u < cnt;
#pragma unroll
            for (int d = 0; d < 8; ++d) a[d] += v ? bf2f(p[u][d]) : 0.f;
        }
#pragma unroll
        for (int u = 0; u < 8; ++u) {
            bool v = 8 + u < cnt;
#pragma unroll
            for (int d = 0; d < 8; ++d) a[d] += v ? bf2f(q[u][d]) : 0.f;
        }
    }

#pragma unroll
    for (int d = 0; d < 8; ++d) a[d] *= dd;

    if (!POOL) {
        if (valid) {
            bf16x8 o;
#pragma unroll
            for (int d = 0; d < 8; ++d) o[d] = f2bf(a[d]);
            *(bf16x8*)&oh[(size_t)node * 128 + li * 8] = o;
        }
        return;
    }

    {
        float4 b0 = ((const float4*)bias)[li * 2];
        float4 b1 = ((const float4*)bias)[li * 2 + 1];
        a[0] = fmaxf(a[0] + b0.x, 0.f); a[1] = fmaxf(a[1] + b0.y, 0.f);
        a[2] = fmaxf(a[2] + b0.z, 0.f); a[3] = fmaxf(a[3] + b0.w, 0.f);
        a[4] = fmaxf(a[4] + b1.x, 0.f); a[5] = fmaxf(a[5] + b1.y, 0.f);
        a[6] = fmaxf(a[6] + b1.z, 0.f); a[7] = fmaxf(a[7] + b1.w, 0.f);
    }
    if (li == 0) sgid[nib] = valid ? batch[node] : -1;
#pragma unroll
    for (int d = 0; d < 8; ++d) pacc[nib][li * 8 + d] = a[d];
    __syncthreads();
    if (tid < 128) {
        int c = tid;
        int cur = sgid[0];
        float run = 0.f;
#pragma unroll 1
        for (int w = 0; w < 16; ++w) {
            int gi = sgid[w];
            if (gi < 0) break;
            if (gi != cur) { atomicAdd(&pool[cur * HID2 + c], run); run = 0.f; cur = gi; }
            run += pacc[w][c];
        }
        atomicAdd(&pool[cur * HID2 + c], run);
    }
}

// ---------------- fc ----------------

__device__ __forceinline__ int lower_bound_i(const int* __restrict__ a, int n, int key) {
    int lo = 0, hi = n;
    while (lo < hi) {
        int mid = (lo + hi) >> 1;
        if (a[mid] < key) lo = mid + 1; else hi = mid;
    }
    return lo;
}

__global__ void fc_kernel(const float* __restrict__ pool, const int* __restrict__ batch,
                          const float* __restrict__ Wfc, const float* __restrict__ bfc,
                          float* __restrict__ out, int N) {
    int t = threadIdx.x;  // 256 = 64 graphs * 4 outputs
    int g = t >> 2, o = t & 3;
    int lo = lower_bound_i(batch, N, g);
    int hi = lower_bound_i(batch, N, g + 1);
    float acc = 0.f;
#pragma unroll 8
    for (int c = 0; c < HID2; ++c)
        acc = fmaf(pool[g * HID2 + c], Wfc[c * OUT_DIM + o], acc);
    float inv = 1.0f / fmaxf((float)(hi - lo), 1.0f);
    out[g * OUT_DIM + o] = acc * inv + bfc[o];
}

extern "C" void kernel_launch(void* const* d_in, const int* in_sizes, int n_in,
                              void* d_out, int out_size, void* d_ws, size_t ws_size,
                              hipStream_t stream) {
    const float* x   = (const float*)d_in[0];
    const int* src   = (const int*)d_in[1];
    const int* dst   = (const int*)d_in[2];
    const int* batch = (const int*)d_in[3];
    const float* W1  = (const float*)d_in[4];
    const float* b1  = (const float*)d_in[5];
    const float* W2  = (const float*)d_in[6];
    const float* b2  = (const float*)d_in[7];
    const float* Wfc = (const float*)d_in[8];
    const float* bfc = (const float*)d_in[9];
    float* out = (float*)d_out;

    const int N = in_sizes[0] / IN_DIM;  // 50000
    const int E = in_sizes[1];           // 640000
    const int NB = (N + 255) / 256;      // scan blocks (196)
    const int GA = (N + 15) / 16;        // agg blocks (3125; 16 nodes each)
    const int GM = (N + 63) / 64;        // fused-MLP blocks (782)

    // ---- workspace layout (~30 MB; region aliasing) ----
    char* ws = (char*)d_ws;
    size_t off = 0;
    auto alloc = [&](size_t bytes) {
        char* p = ws + off;
        off = (off + bytes + 255) & ~(size_t)255;
        return p;
    };
    float*  dinv   = (float*) alloc((size_t)N * 4);
    int*    count  = (int*)   alloc((size_t)N * 4);
    int*    rowptr = (int*)   alloc((size_t)(N + 1) * 4);
    int*    bsums  = (int*)   alloc(256 * 4);
    ushort* rank   = (ushort*)alloc((size_t)E * 2);
    ushort* csr    = (ushort*)alloc((size_t)E * 2);
    short*  W1th   = (short*) alloc((size_t)IN_DIM * HID * 2);
    short*  W1tl   = (short*) alloc((size_t)IN_DIM * HID * 2);
    short*  W2th   = (short*) alloc((size_t)HID * HID2 * 2);
    short*  W2tl   = (short*) alloc((size_t)HID * HID2 * 2);
    // region Z (12.8 MB): xb -> later h2b (bf16)
    ushort* xb     = (ushort*)alloc((size_t)N * IN_DIM * 2);
    // region X (12.8 MB): axb (bf16, agg1 out)
    short*  axb    = (short*) alloc((size_t)N * IN_DIM * 2);
    float*  pool   = (float*) alloc((size_t)NGRAPH * HID2 * 4);
    ushort* h2b = xb;              // xb dead after agg1

    // ---- weight prep + count zero + pool zero ----
    wprep_all_kernel<<<(max(IN_DIM * HID, N) + 255) / 256, 256, 0, stream>>>(
        W1, W1th, W1tl, W2, W2th, W2tl, count, pool, N);

    // ---- CSR build (once; serves both layers) ----
    hist_kernel<<<(E + 255) / 256, 256, 0, stream>>>(dst, count, rank, E);
    scan1_kernel<<<NB, 256, 0, stream>>>(count, bsums, N);
    scan3_kernel<<<NB, 256, 0, stream>>>(count, bsums, rowptr, dinv, N, E, NB);
    scatter_scale_kernel<<<(N * 64 + 255) / 256, 256, 0, stream>>>(
        src, dst, rank, rowptr, csr, x, dinv, xb, E, N * 64);

    // ---- layer 1 agg ----
    agg_group_kernel<false><<<GA, 256, 0, stream>>>(
        xb, dinv, rowptr, csr, nullptr, axb, nullptr, nullptr, N);

    // ---- fused MLP (gemm1 + gemm2) ----
    mlp_fused_kernel<<<GM, 256, 0, stream>>>(
        axb, W1th, W1tl, b1, W2th, W2tl, dinv, (short*)h2b, N);

    // ---- layer 2 agg + pool ----
    agg_group_kernel<true><<<GA, 256, 0, stream>>>(
        h2b, dinv, rowptr, csr, b2, nullptr, batch, pool, N);

    // ---- fc ----
    fc_kernel<<<1, NGRAPH * OUT_DIM, 0, stream>>>(pool, batch, Wfc, bfc, out, N);
}